// Round 1
// 2071.365 us; speedup vs baseline: 1.2245x; 1.2245x over previous
//
#include <hip/hip_runtime.h>
#include <cstdint>
#include <cstddef>

// ---------------------------------------------------------------------------
// HippocampusModule: query->adapter->MLP(GELU)->key proj->softmax attention
// over 65536-slot memory -> concat -> retriever MLP(GELU).
//  - softmax unnormalized: P = exp(logits) (bounded ~e^±0.5), rowsum via
//    ones-MFMA (FIXED: only one wave per row-stripe writes it; the previous
//    version double-counted -> retrieved was halved, absmax 0.0029).
//  - R3: P stored fp8 e4m3 (halves HBM traffic + LDS), memv^T fp8; PV kernel
//    uses mfma fp8_fp8 with double-buffered LDS + issue-early prefetch
//    (2-phase pipeline) to attack the latency-bound 26% MfmaUtil.
// ---------------------------------------------------------------------------

#define EMB 768
#define HID 1024
#define MEMN 65536
#define NQ 4096
#define KSPLIT 8

typedef _Float16 half8 __attribute__((ext_vector_type(8)));
typedef _Float16 half4v __attribute__((ext_vector_type(4)));
typedef float float4v __attribute__((ext_vector_type(4)));

// ---------------- conversion kernels ----------------

__global__ void cvt_f32_to_f16(const float* __restrict__ in,
                               _Float16* __restrict__ out, size_t n) {
  size_t i = ((size_t)blockIdx.x * blockDim.x + threadIdx.x) * 4;
  if (i >= n) return;
  float4 v = *(const float4*)(in + i);
  half4v h;
  h[0] = (_Float16)v.x; h[1] = (_Float16)v.y;
  h[2] = (_Float16)v.z; h[3] = (_Float16)v.w;
  *(half4v*)(out + i) = h;
}

// out[C][R] (fp16) = transpose of in[R][C] (fp32). R,C multiples of 32.
__global__ void transpose_cvt(const float* __restrict__ in,
                              _Float16* __restrict__ out, int R, int C) {
  __shared__ float t[32][33];
  int tx = threadIdx.x, ty = threadIdx.y;
  int c0 = blockIdx.x * 32, r0 = blockIdx.y * 32;
#pragma unroll
  for (int k = 0; k < 4; ++k) {
    int r = r0 + ty + k * 8;
    t[ty + k * 8][tx] = in[(size_t)r * C + c0 + tx];
  }
  __syncthreads();
#pragma unroll
  for (int k = 0; k < 4; ++k) {
    int ro = c0 + ty + k * 8;  // output row == input col
    out[(size_t)ro * R + r0 + tx] = (_Float16)t[tx][ty + k * 8];
  }
}

// out[C][R] (fp8 e4m3) = transpose of in[R][C] (fp32).
__global__ void transpose_cvt_f8(const float* __restrict__ in,
                                 uint8_t* __restrict__ out, int R, int C) {
  __shared__ float t[32][33];
  int tx = threadIdx.x, ty = threadIdx.y;
  int c0 = blockIdx.x * 32, r0 = blockIdx.y * 32;
#pragma unroll
  for (int k = 0; k < 4; ++k) {
    int r = r0 + ty + k * 8;
    t[ty + k * 8][tx] = in[(size_t)r * C + c0 + tx];
  }
  __syncthreads();
#pragma unroll
  for (int k = 0; k < 4; ++k) {
    int ro = c0 + ty + k * 8;
    float v = t[tx][ty + k * 8];
    int pk = __builtin_amdgcn_cvt_pk_fp8_f32(v, v, 0, false);
    out[(size_t)ro * R + r0 + tx] = (uint8_t)(pk & 0xff);
  }
}

// comb16 right half = fp16(O32 / rs32)
__global__ void normalize_out(const float* __restrict__ O32,
                              const float* __restrict__ rs32,
                              _Float16* __restrict__ comb) {
  size_t i = ((size_t)blockIdx.x * blockDim.x + threadIdx.x) * 4;
  size_t row = i >> 10;
  size_t c = i & 1023;
  float4 v = *(const float4*)(O32 + i);
  float inv = 1.0f / rs32[row];
  half4v h;
  h[0] = (_Float16)(v.x * inv); h[1] = (_Float16)(v.y * inv);
  h[2] = (_Float16)(v.z * inv); h[3] = (_Float16)(v.w * inv);
  *(half4v*)(comb + row * 2048 + 1024 + c) = h;
}

// ---------------- GEMM ----------------

enum { EPI_H16 = 0, EPI_GELU_H16 = 1, EPI_EXP_F8 = 2, EPI_F32 = 4 };

__device__ __forceinline__ void global_to_lds16(const void* g, void* l) {
  __builtin_amdgcn_global_load_lds(
      (const __attribute__((address_space(1))) void*)g,
      (__attribute__((address_space(3))) void*)l, 16, 0, 0);
}

__device__ __forceinline__ float gelu_erf(float x) {
  return 0.5f * x * (1.0f + erff(x * 0.7071067811865475f));
}

// C[M,N] = epilogue(A[M,K] @ BT[N,K]^T).  M,N multiples of 128, K of 64.
// grid = (N/128, M/128), block = 256 (4 waves, 2x2 of 64x64, each 4x4 MFMAs).
template <int EPI>
__global__ __launch_bounds__(256) void gemm_bt(
    const _Float16* __restrict__ A, int lda, const _Float16* __restrict__ BT,
    int ldb, const float* __restrict__ bias, void* __restrict__ Cout, int ldc,
    int K, float scale) {
  __shared__ __align__(16) _Float16 sA[128 * 64];
  __shared__ __align__(16) _Float16 sB[128 * 64];

  const int tid = threadIdx.x;
  const int lane = tid & 63;
  const int wave = tid >> 6;
  const int quad = lane >> 4;
  const int m16 = lane & 15;
  const int wm = (wave >> 1) * 64;
  const int wn = (wave & 1) * 64;

  const size_t rowBase = (size_t)blockIdx.y * 128;
  const size_t colBase = (size_t)blockIdx.x * 128;

  const int srow = lane >> 3;
  const int sg = (lane & 7) ^ srow;  // XOR-swizzled 16B granule slot

  const _Float16* Abase[4];
  const _Float16* Bbase[4];
#pragma unroll
  for (int q = 0; q < 4; ++q) {
    int t = wave * 4 + q;
    Abase[q] = A + (rowBase + 8 * t + srow) * (size_t)lda + sg * 8;
    Bbase[q] = BT + (colBase + 8 * t + srow) * (size_t)ldb + sg * 8;
  }

  float4v acc[4][4] = {};

  for (int k0 = 0; k0 < K; k0 += 64) {
    __syncthreads();
#pragma unroll
    for (int q = 0; q < 4; ++q) {
      int t = wave * 4 + q;
      global_to_lds16(Abase[q] + k0, &sA[t * 512 + lane * 8]);
      global_to_lds16(Bbase[q] + k0, &sB[t * 512 + lane * 8]);
    }
    __syncthreads();

#pragma unroll
    for (int kk = 0; kk < 2; ++kk) {
      half8 af[4], bf[4];
      const int pg = kk * 4 + quad;
      const int ps = pg ^ (m16 & 7);
#pragma unroll
      for (int i = 0; i < 4; ++i)
        af[i] = *(const half8*)&sA[(wm + i * 16 + m16) * 64 + ps * 8];
#pragma unroll
      for (int j = 0; j < 4; ++j)
        bf[j] = *(const half8*)&sB[(wn + j * 16 + m16) * 64 + ps * 8];
#pragma unroll
      for (int i = 0; i < 4; ++i)
#pragma unroll
        for (int j = 0; j < 4; ++j)
          acc[i][j] =
              __builtin_amdgcn_mfma_f32_16x16x32_f16(af[i], bf[j], acc[i][j], 0, 0, 0);
    }
  }

  // Epilogue. C/D layout: col = lane&15, row = quad*4 + reg (within 16x16).
#pragma unroll
  for (int i = 0; i < 4; ++i) {
#pragma unroll
    for (int j = 0; j < 4; ++j) {
      size_t c = colBase + wn + j * 16 + m16;
      float bv = (EPI == EPI_EXP_F8) ? 0.0f : bias[c];
#pragma unroll
      for (int rr = 0; rr < 4; ++rr) {
        size_t row = rowBase + wm + i * 16 + quad * 4 + rr;
        float x = acc[i][j][rr];
        if (EPI != EPI_EXP_F8) x += bv;
        if (EPI == EPI_GELU_H16) x = gelu_erf(x);
        if (EPI == EPI_EXP_F8) {
          x = expf(x * scale);
          int pk = __builtin_amdgcn_cvt_pk_fp8_f32(x, x, 0, false);
          ((uint8_t*)Cout)[row * (size_t)ldc + c] = (uint8_t)(pk & 0xff);
        } else if (EPI == EPI_F32) {
          ((float*)Cout)[row * (size_t)ldc + c] = x;
        } else {
          ((_Float16*)Cout)[row * (size_t)ldc + c] = (_Float16)x;
        }
      }
    }
  }
}

// Split-K P@V in fp8: O32[M,1024] += P[M,K] @ VT[1024,K]^T (fp32 atomics),
// rs32[M] += rowsum(P) via ones-MFMA (n-block 0, even waves only).
// Double-buffered LDS, prefetch issued before compute (2-phase pipeline).
// 1-D grid; the 8 N-blocks of one (m,kslice) group land on ids congruent
// mod 8 -> same XCD -> shared-L2 P-slice reuse.
__global__ __launch_bounds__(256, 4) void gemm_pv_splitk_fp8(
    const uint8_t* __restrict__ P, const uint8_t* __restrict__ VT,
    float* __restrict__ O32, float* __restrict__ rs32, int Kslice,
    int mBlocks) {
  __shared__ __align__(16) uint8_t sA[2][128 * 64];
  __shared__ __align__(16) uint8_t sB[2][128 * 64];

  const int id = blockIdx.x;
  const int c8 = id & 7;
  const int nb = (id >> 3) & 7;
  const int g = (id >> 6) * 8 + c8;  // group = (m, kslice)
  const int mb = g % mBlocks;
  const int ks = g / mBlocks;

  const int tid = threadIdx.x;
  const int lane = tid & 63;
  const int wave = tid >> 6;
  const int quad = lane >> 4;
  const int m16 = lane & 15;
  const int wm = (wave >> 1) * 64;
  const int wn = (wave & 1) * 64;

  const size_t rowBase = (size_t)mb * 128;
  const size_t colBase = (size_t)nb * 128;
  const int kBeg = ks * Kslice;

  // Staging: per wave, 2 calls x 16 rows x 64B for A and for B.
  // Lane l: row-in-call = l>>2, 16B granule g16 = l&3, source granule
  // swizzled gs = g16 ^ ((row>>1)&3)  (read side: g8' = g8 ^ (row&6)).
  const int srow = lane >> 2;
  const int g16 = lane & 3;
  const uint8_t* Asrc[2];
  const uint8_t* Bsrc[2];
  int dOff[2];
#pragma unroll
  for (int c = 0; c < 2; ++c) {
    int tr = wave * 32 + c * 16 + srow;
    int gs = g16 ^ ((tr >> 1) & 3);
    Asrc[c] = P + (rowBase + tr) * (size_t)MEMN + kBeg + gs * 16;
    Bsrc[c] = VT + (colBase + tr) * (size_t)MEMN + kBeg + gs * 16;
    dOff[c] = tr * 64 + g16 * 16;
  }

  auto stage = [&](int buf, int k0) {
#pragma unroll
    for (int c = 0; c < 2; ++c) {
      global_to_lds16(Asrc[c] + k0, &sA[buf][dOff[c]]);
      global_to_lds16(Bsrc[c] + k0, &sB[buf][dOff[c]]);
    }
  };

  float4v acc[4][4] = {};
  float4v accrs[4] = {};
  // rowsum only once per row-stripe: nb==0 AND even wave (waves 0/1 share wm!)
  const bool doRS = (nb == 0) && ((wave & 1) == 0);
  const long vone = 0x3838383838383838L;  // 8x fp8 e4m3 1.0

  const int nsteps = Kslice / 64;
  stage(0, 0);
  __syncthreads();  // drains vmcnt -> buf0 ready

  int cur = 0;
  for (int step = 0; step < nsteps; ++step) {
    if (step + 1 < nsteps) stage(cur ^ 1, (step + 1) * 64);  // issue, in flight

#pragma unroll
    for (int kk = 0; kk < 2; ++kk) {
      const int g8 = (kk * 4 + quad) ^ (m16 & 6);
      long af[4], bf[4];
#pragma unroll
      for (int i = 0; i < 4; ++i)
        af[i] = *(const long*)&sA[cur][(wm + i * 16 + m16) * 64 + g8 * 8];
#pragma unroll
      for (int j = 0; j < 4; ++j)
        bf[j] = *(const long*)&sB[cur][(wn + j * 16 + m16) * 64 + g8 * 8];
#pragma unroll
      for (int i = 0; i < 4; ++i) {
#pragma unroll
        for (int j = 0; j < 4; ++j)
          acc[i][j] = __builtin_amdgcn_mfma_f32_16x16x32_fp8_fp8(
              af[i], bf[j], acc[i][j], 0, 0, 0);
        if (doRS)
          accrs[i] = __builtin_amdgcn_mfma_f32_16x16x32_fp8_fp8(
              af[i], vone, accrs[i], 0, 0, 0);
      }
    }

    __syncthreads();  // drains prefetch (overlapped with MFMAs above)
    cur ^= 1;
  }

#pragma unroll
  for (int i = 0; i < 4; ++i) {
#pragma unroll
    for (int j = 0; j < 4; ++j) {
      size_t c = colBase + wn + j * 16 + m16;
#pragma unroll
      for (int rr = 0; rr < 4; ++rr) {
        size_t row = rowBase + wm + i * 16 + quad * 4 + rr;
        atomicAdd(&O32[row * 1024 + c], acc[i][j][rr]);
      }
    }
    if (doRS && m16 == 0) {
#pragma unroll
      for (int rr = 0; rr < 4; ++rr) {
        size_t row = rowBase + wm + i * 16 + quad * 4 + rr;
        atomicAdd(&rs32[row], accrs[i][rr]);
      }
    }
  }
}

// ---------------- launch ----------------

static inline void* wsalloc(char*& p, size_t bytes) {
  void* r = (void*)p;
  p += (bytes + 255) & ~(size_t)255;
  return r;
}

extern "C" void kernel_launch(void* const* d_in, const int* in_sizes, int n_in,
                              void* d_out, int out_size, void* d_ws,
                              size_t ws_size, hipStream_t stream) {
  const float* query = (const float*)d_in[0];
  const float* W_in = (const float*)d_in[1];
  const float* b_in = (const float*)d_in[2];
  const float* W_e1 = (const float*)d_in[3];
  const float* b_e1 = (const float*)d_in[4];
  const float* W_e2 = (const float*)d_in[5];
  const float* b_e2 = (const float*)d_in[6];
  const float* W_k = (const float*)d_in[7];
  const float* b_k = (const float*)d_in[8];
  const float* memk = (const float*)d_in[9];
  const float* memv = (const float*)d_in[10];
  const float* W_r1 = (const float*)d_in[11];
  const float* b_r1 = (const float*)d_in[12];
  const float* W_r2 = (const float*)d_in[13];
  const float* b_r2 = (const float*)d_in[14];
  float* out = (float*)d_out;

  char* p = (char*)d_ws;
  _Float16* q16 = (_Float16*)wsalloc(p, (size_t)NQ * EMB * 2);
  _Float16* WinT = (_Float16*)wsalloc(p, (size_t)HID * EMB * 2);
  _Float16* We1T = (_Float16*)wsalloc(p, (size_t)2 * HID * HID * 2);
  _Float16* We2T = (_Float16*)wsalloc(p, (size_t)HID * 2 * HID * 2);
  _Float16* WkT = (_Float16*)wsalloc(p, (size_t)HID * HID * 2);
  _Float16* Wr1T = (_Float16*)wsalloc(p, (size_t)2 * HID * 2 * HID * 2);
  _Float16* Wr2T = (_Float16*)wsalloc(p, (size_t)EMB * 2 * HID * 2);
  _Float16* memk16 = (_Float16*)wsalloc(p, (size_t)MEMN * HID * 2);
  uint8_t* memvT8 = (uint8_t*)wsalloc(p, (size_t)HID * MEMN);
  _Float16* x16 = (_Float16*)wsalloc(p, (size_t)NQ * HID * 2);
  _Float16* h16 = (_Float16*)wsalloc(p, (size_t)NQ * 2 * HID * 2);
  _Float16* key16 = (_Float16*)wsalloc(p, (size_t)NQ * HID * 2);
  _Float16* comb16 = (_Float16*)wsalloc(p, (size_t)NQ * 2 * HID * 2);
  _Float16* r16 = (_Float16*)wsalloc(p, (size_t)NQ * 2 * HID * 2);
  float* O32 = (float*)wsalloc(p, (size_t)NQ * HID * 4);
  float* rs32 = (float*)wsalloc(p, (size_t)NQ * 4);

  // P buffer (fp8): chunk M if ws is too small (constant per ws_size).
  size_t fixedBytes = (size_t)(p - (char*)d_ws);
  size_t Mc = NQ;
  while (Mc > 128 && fixedBytes + Mc * (size_t)MEMN > ws_size) Mc >>= 1;
  uint8_t* P8 = (uint8_t*)wsalloc(p, Mc * (size_t)MEMN);

  auto cvt = [&](const float* in, _Float16* o, size_t n) {
    cvt_f32_to_f16<<<dim3((unsigned)((n / 4 + 255) / 256)), 256, 0, stream>>>(in, o, n);
  };
  auto tr = [&](const float* in, _Float16* o, int R, int C) {
    transpose_cvt<<<dim3(C / 32, R / 32), dim3(32, 8), 0, stream>>>(in, o, R, C);
  };

  cvt(query, q16, (size_t)NQ * EMB);
  cvt(memk, memk16, (size_t)MEMN * HID);
  tr(W_in, WinT, EMB, HID);
  tr(W_e1, We1T, HID, 2 * HID);
  tr(W_e2, We2T, 2 * HID, HID);
  tr(W_k, WkT, HID, HID);
  tr(W_r1, Wr1T, 2 * HID, 2 * HID);
  tr(W_r2, Wr2T, 2 * HID, EMB);
  transpose_cvt_f8<<<dim3(HID / 32, MEMN / 32), dim3(32, 8), 0, stream>>>(
      memv, memvT8, MEMN, HID);

  // x = query @ W_in + b_in
  gemm_bt<EPI_H16><<<dim3(HID / 128, NQ / 128), 256, 0, stream>>>(
      q16, EMB, WinT, EMB, b_in, x16, HID, EMB, 0.f);
  // h = gelu(x @ W_e1 + b_e1)
  gemm_bt<EPI_GELU_H16><<<dim3(2 * HID / 128, NQ / 128), 256, 0, stream>>>(
      x16, HID, We1T, HID, b_e1, h16, 2 * HID, HID, 0.f);
  // encoded = h @ W_e2 + b_e2  -> left half of combined (ldc = 2*HID)
  gemm_bt<EPI_H16><<<dim3(HID / 128, NQ / 128), 256, 0, stream>>>(
      h16, 2 * HID, We2T, 2 * HID, b_e2, comb16, 2 * HID, 2 * HID, 0.f);
  // key = encoded @ W_k + b_k   (A = combined left half via lda = 2*HID)
  gemm_bt<EPI_H16><<<dim3(HID / 128, NQ / 128), 256, 0, stream>>>(
      comb16, 2 * HID, WkT, HID, b_k, key16, HID, HID, 0.f);

  // zero attention accumulators (harness poisons ws every call)
  hipMemsetAsync(O32, 0, (size_t)NQ * HID * 4, stream);
  hipMemsetAsync(rs32, 0, (size_t)NQ * 4, stream);

  const float scale = 0.03125f;  // 1/sqrt(HID)
  const int Kslice = MEMN / KSPLIT;
  for (size_t m0 = 0; m0 < NQ; m0 += Mc) {
    // P = fp8(exp(scale * key @ memk^T))   [Mc, MEMN]
    gemm_bt<EPI_EXP_F8><<<dim3(MEMN / 128, (unsigned)(Mc / 128)), 256, 0, stream>>>(
        key16 + m0 * HID, HID, memk16, HID, nullptr, P8, MEMN, HID, scale);
    // O32[m0..] += P @ memv (split-K, fp32 atomics); rs32 += rowsum(P)
    int mBlocks = (int)(Mc / 128);
    gemm_pv_splitk_fp8<<<dim3((unsigned)(mBlocks * KSPLIT * 8)), 256, 0, stream>>>(
        P8, memvT8, O32 + m0 * HID, rs32 + m0, Kslice, mBlocks);
  }

  // retrieved = O32 / rs32 -> right half of combined
  normalize_out<<<dim3(NQ * HID / 4 / 256), 256, 0, stream>>>(O32, rs32, comb16);

  // r = gelu(combined @ W_r1 + b_r1)
  gemm_bt<EPI_GELU_H16><<<dim3(2 * HID / 128, NQ / 128), 256, 0, stream>>>(
      comb16, 2 * HID, Wr1T, 2 * HID, b_r1, r16, 2 * HID, 2 * HID, 0.f);
  // result = r @ W_r2 + b_r2  (fp32 out)
  gemm_bt<EPI_F32><<<dim3(EMB / 128, NQ / 128), 256, 0, stream>>>(
      r16, 2 * HID, Wr2T, 2 * HID, b_r2, out, EMB, 2 * HID, 0.f);

  (void)in_sizes; (void)n_in; (void)out_size;
}

// Round 2
// 1845.351 us; speedup vs baseline: 1.3744x; 1.1225x over previous
//
#include <hip/hip_runtime.h>
#include <cstdint>
#include <cstddef>

// ---------------------------------------------------------------------------
// HippocampusModule: query->adapter->MLP(GELU)->key proj->softmax attention
// over 65536-slot memory -> concat -> retriever MLP(GELU).
//  - softmax unnormalized: P = exp(logits) (bounded ~e^±0.5), rowsum via
//    ones-MFMA (one wave per row-stripe writes it).
//  - R3: P fp8 e4m3, memv^T fp8; PV = fp8 MFMA + double-buffered 2-phase.
//  - R4: QK GEMM also fp8 (key8 via EPI_H8 epilogue, memk8 direct cvt) with
//    the same 2-phase double-buffer + XCD-affinity grid (all m-stripes of a
//    memk tile on one XCD -> B-tile fetched once from HBM, L2-served after).
//    Attacks QK's 2.12 GB fetch (memk re-streamed 16x) + 1-phase stall.
// ---------------------------------------------------------------------------

#define EMB 768
#define HID 1024
#define MEMN 65536
#define NQ 4096
#define KSPLIT 8

typedef _Float16 half8 __attribute__((ext_vector_type(8)));
typedef _Float16 half4v __attribute__((ext_vector_type(4)));
typedef float float4v __attribute__((ext_vector_type(4)));

// ---------------- conversion kernels ----------------

__global__ void cvt_f32_to_f16(const float* __restrict__ in,
                               _Float16* __restrict__ out, size_t n) {
  size_t i = ((size_t)blockIdx.x * blockDim.x + threadIdx.x) * 4;
  if (i >= n) return;
  float4 v = *(const float4*)(in + i);
  half4v h;
  h[0] = (_Float16)v.x; h[1] = (_Float16)v.y;
  h[2] = (_Float16)v.z; h[3] = (_Float16)v.w;
  *(half4v*)(out + i) = h;
}

__global__ void cvt_f32_to_f8(const float* __restrict__ in,
                              uint8_t* __restrict__ out, size_t n) {
  size_t i = ((size_t)blockIdx.x * blockDim.x + threadIdx.x) * 4;
  if (i >= n) return;
  float4 v = *(const float4*)(in + i);
  int lo = __builtin_amdgcn_cvt_pk_fp8_f32(v.x, v.y, 0, false);
  int hi = __builtin_amdgcn_cvt_pk_fp8_f32(v.z, v.w, 0, false);
  uint32_t w = (uint32_t)(lo & 0xffff) | ((uint32_t)hi << 16);
  *(uint32_t*)(out + i) = w;
}

// out[C][R] (fp16) = transpose of in[R][C] (fp32). R,C multiples of 32.
__global__ void transpose_cvt(const float* __restrict__ in,
                              _Float16* __restrict__ out, int R, int C) {
  __shared__ float t[32][33];
  int tx = threadIdx.x, ty = threadIdx.y;
  int c0 = blockIdx.x * 32, r0 = blockIdx.y * 32;
#pragma unroll
  for (int k = 0; k < 4; ++k) {
    int r = r0 + ty + k * 8;
    t[ty + k * 8][tx] = in[(size_t)r * C + c0 + tx];
  }
  __syncthreads();
#pragma unroll
  for (int k = 0; k < 4; ++k) {
    int ro = c0 + ty + k * 8;  // output row == input col
    out[(size_t)ro * R + r0 + tx] = (_Float16)t[tx][ty + k * 8];
  }
}

// out[C][R] (fp8 e4m3) = transpose of in[R][C] (fp32).
__global__ void transpose_cvt_f8(const float* __restrict__ in,
                                 uint8_t* __restrict__ out, int R, int C) {
  __shared__ float t[32][33];
  int tx = threadIdx.x, ty = threadIdx.y;
  int c0 = blockIdx.x * 32, r0 = blockIdx.y * 32;
#pragma unroll
  for (int k = 0; k < 4; ++k) {
    int r = r0 + ty + k * 8;
    t[ty + k * 8][tx] = in[(size_t)r * C + c0 + tx];
  }
  __syncthreads();
#pragma unroll
  for (int k = 0; k < 4; ++k) {
    int ro = c0 + ty + k * 8;
    float v = t[tx][ty + k * 8];
    int pk = __builtin_amdgcn_cvt_pk_fp8_f32(v, v, 0, false);
    out[(size_t)ro * R + r0 + tx] = (uint8_t)(pk & 0xff);
  }
}

// comb16 right half = fp16(O32 / rs32)
__global__ void normalize_out(const float* __restrict__ O32,
                              const float* __restrict__ rs32,
                              _Float16* __restrict__ comb) {
  size_t i = ((size_t)blockIdx.x * blockDim.x + threadIdx.x) * 4;
  size_t row = i >> 10;
  size_t c = i & 1023;
  float4 v = *(const float4*)(O32 + i);
  float inv = 1.0f / rs32[row];
  half4v h;
  h[0] = (_Float16)(v.x * inv); h[1] = (_Float16)(v.y * inv);
  h[2] = (_Float16)(v.z * inv); h[3] = (_Float16)(v.w * inv);
  *(half4v*)(comb + row * 2048 + 1024 + c) = h;
}

// ---------------- GEMM ----------------

enum { EPI_H16 = 0, EPI_GELU_H16 = 1, EPI_F32 = 4, EPI_H8 = 5 };

__device__ __forceinline__ void global_to_lds16(const void* g, void* l) {
  __builtin_amdgcn_global_load_lds(
      (const __attribute__((address_space(1))) void*)g,
      (__attribute__((address_space(3))) void*)l, 16, 0, 0);
}

__device__ __forceinline__ float gelu_erf(float x) {
  return 0.5f * x * (1.0f + erff(x * 0.7071067811865475f));
}

// C[M,N] = epilogue(A[M,K] @ BT[N,K]^T).  M,N multiples of 128, K of 64.
// grid = (N/128, M/128), block = 256 (4 waves, 2x2 of 64x64, each 4x4 MFMAs).
template <int EPI>
__global__ __launch_bounds__(256) void gemm_bt(
    const _Float16* __restrict__ A, int lda, const _Float16* __restrict__ BT,
    int ldb, const float* __restrict__ bias, void* __restrict__ Cout, int ldc,
    int K, float scale) {
  __shared__ __align__(16) _Float16 sA[128 * 64];
  __shared__ __align__(16) _Float16 sB[128 * 64];

  const int tid = threadIdx.x;
  const int lane = tid & 63;
  const int wave = tid >> 6;
  const int quad = lane >> 4;
  const int m16 = lane & 15;
  const int wm = (wave >> 1) * 64;
  const int wn = (wave & 1) * 64;

  const size_t rowBase = (size_t)blockIdx.y * 128;
  const size_t colBase = (size_t)blockIdx.x * 128;

  const int srow = lane >> 3;
  const int sg = (lane & 7) ^ srow;  // XOR-swizzled 16B granule slot

  const _Float16* Abase[4];
  const _Float16* Bbase[4];
#pragma unroll
  for (int q = 0; q < 4; ++q) {
    int t = wave * 4 + q;
    Abase[q] = A + (rowBase + 8 * t + srow) * (size_t)lda + sg * 8;
    Bbase[q] = BT + (colBase + 8 * t + srow) * (size_t)ldb + sg * 8;
  }

  float4v acc[4][4] = {};

  for (int k0 = 0; k0 < K; k0 += 64) {
    __syncthreads();
#pragma unroll
    for (int q = 0; q < 4; ++q) {
      int t = wave * 4 + q;
      global_to_lds16(Abase[q] + k0, &sA[t * 512 + lane * 8]);
      global_to_lds16(Bbase[q] + k0, &sB[t * 512 + lane * 8]);
    }
    __syncthreads();

#pragma unroll
    for (int kk = 0; kk < 2; ++kk) {
      half8 af[4], bf[4];
      const int pg = kk * 4 + quad;
      const int ps = pg ^ (m16 & 7);
#pragma unroll
      for (int i = 0; i < 4; ++i)
        af[i] = *(const half8*)&sA[(wm + i * 16 + m16) * 64 + ps * 8];
#pragma unroll
      for (int j = 0; j < 4; ++j)
        bf[j] = *(const half8*)&sB[(wn + j * 16 + m16) * 64 + ps * 8];
#pragma unroll
      for (int i = 0; i < 4; ++i)
#pragma unroll
        for (int j = 0; j < 4; ++j)
          acc[i][j] =
              __builtin_amdgcn_mfma_f32_16x16x32_f16(af[i], bf[j], acc[i][j], 0, 0, 0);
    }
  }

  // Epilogue. C/D layout: col = lane&15, row = quad*4 + reg (within 16x16).
#pragma unroll
  for (int i = 0; i < 4; ++i) {
#pragma unroll
    for (int j = 0; j < 4; ++j) {
      size_t c = colBase + wn + j * 16 + m16;
      float bv = bias[c];
#pragma unroll
      for (int rr = 0; rr < 4; ++rr) {
        size_t row = rowBase + wm + i * 16 + quad * 4 + rr;
        float x = acc[i][j][rr] + bv;
        if (EPI == EPI_GELU_H16) x = gelu_erf(x);
        if (EPI == EPI_F32) {
          ((float*)Cout)[row * (size_t)ldc + c] = x;
        } else if (EPI == EPI_H8) {
          int pk = __builtin_amdgcn_cvt_pk_fp8_f32(x, x, 0, false);
          ((uint8_t*)Cout)[row * (size_t)ldc + c] = (uint8_t)(pk & 0xff);
        } else {
          ((_Float16*)Cout)[row * (size_t)ldc + c] = (_Float16)x;
        }
      }
    }
  }
  (void)scale;
}

// QK in fp8: P8[M,MEMN] = fp8(exp(scale * (key8 @ memk8^T))).
// Same 2-phase double-buffered fp8 core as gemm_pv_splitk_fp8 (verified).
// 1-D grid; the ny m-stripes of one memk column-tile land on ids congruent
// mod 8 -> same XCD -> B-tile fetched from HBM once, then L2-served.
__global__ __launch_bounds__(256, 4) void gemm_qk_fp8(
    const uint8_t* __restrict__ A8, const uint8_t* __restrict__ BT8,
    uint8_t* __restrict__ P8, int ny, float scale) {
  __shared__ __align__(16) uint8_t sA[2][128 * 64];
  __shared__ __align__(16) uint8_t sB[2][128 * 64];

  const int id = blockIdx.x;
  const int c8 = id & 7;
  const int rest = id >> 3;
  const int yb = rest % ny;          // m-stripe
  const int xb = (rest / ny) * 8 + c8;  // memk column-tile

  const int tid = threadIdx.x;
  const int lane = tid & 63;
  const int wave = tid >> 6;
  const int quad = lane >> 4;
  const int m16 = lane & 15;
  const int wm = (wave >> 1) * 64;
  const int wn = (wave & 1) * 64;

  const size_t rowBase = (size_t)yb * 128;
  const size_t colBase = (size_t)xb * 128;

  // Staging: per wave, 2 calls x 16 rows x 64B for A and for B.
  // Lane l: row-in-call = l>>2, 16B granule g16 = l&3, source granule
  // swizzled gs = g16 ^ ((row>>1)&3)  (read side: g8' = g8 ^ (row&6)).
  const int srow = lane >> 2;
  const int g16 = lane & 3;
  const uint8_t* Asrc[2];
  const uint8_t* Bsrc[2];
  int dOff[2];
#pragma unroll
  for (int c = 0; c < 2; ++c) {
    int tr = wave * 32 + c * 16 + srow;
    int gs = g16 ^ ((tr >> 1) & 3);
    Asrc[c] = A8 + (rowBase + tr) * (size_t)HID + gs * 16;
    Bsrc[c] = BT8 + (colBase + tr) * (size_t)HID + gs * 16;
    dOff[c] = tr * 64 + g16 * 16;
  }

  auto stage = [&](int buf, int k0) {
#pragma unroll
    for (int c = 0; c < 2; ++c) {
      global_to_lds16(Asrc[c] + k0, &sA[buf][dOff[c]]);
      global_to_lds16(Bsrc[c] + k0, &sB[buf][dOff[c]]);
    }
  };

  float4v acc[4][4] = {};

  const int nsteps = HID / 64;  // 16
  stage(0, 0);
  __syncthreads();

  int cur = 0;
  for (int step = 0; step < nsteps; ++step) {
    if (step + 1 < nsteps) stage(cur ^ 1, (step + 1) * 64);

#pragma unroll
    for (int kk = 0; kk < 2; ++kk) {
      const int g8 = (kk * 4 + quad) ^ (m16 & 6);
      long af[4], bf[4];
#pragma unroll
      for (int i = 0; i < 4; ++i)
        af[i] = *(const long*)&sA[cur][(wm + i * 16 + m16) * 64 + g8 * 8];
#pragma unroll
      for (int j = 0; j < 4; ++j)
        bf[j] = *(const long*)&sB[cur][(wn + j * 16 + m16) * 64 + g8 * 8];
#pragma unroll
      for (int i = 0; i < 4; ++i)
#pragma unroll
        for (int j = 0; j < 4; ++j)
          acc[i][j] = __builtin_amdgcn_mfma_f32_16x16x32_fp8_fp8(
              af[i], bf[j], acc[i][j], 0, 0, 0);
    }

    __syncthreads();
    cur ^= 1;
  }

#pragma unroll
  for (int i = 0; i < 4; ++i) {
#pragma unroll
    for (int j = 0; j < 4; ++j) {
      size_t c = colBase + wn + j * 16 + m16;
#pragma unroll
      for (int rr = 0; rr < 4; ++rr) {
        size_t row = rowBase + wm + i * 16 + quad * 4 + rr;
        float x = expf(acc[i][j][rr] * scale);
        int pk = __builtin_amdgcn_cvt_pk_fp8_f32(x, x, 0, false);
        P8[row * (size_t)MEMN + c] = (uint8_t)(pk & 0xff);
      }
    }
  }
}

// Split-K P@V in fp8: O32[M,1024] += P[M,K] @ VT[1024,K]^T (fp32 atomics),
// rs32[M] += rowsum(P) via ones-MFMA (n-block 0, even waves only).
// Double-buffered LDS, prefetch issued before compute (2-phase pipeline).
__global__ __launch_bounds__(256, 4) void gemm_pv_splitk_fp8(
    const uint8_t* __restrict__ P, const uint8_t* __restrict__ VT,
    float* __restrict__ O32, float* __restrict__ rs32, int Kslice,
    int mBlocks) {
  __shared__ __align__(16) uint8_t sA[2][128 * 64];
  __shared__ __align__(16) uint8_t sB[2][128 * 64];

  const int id = blockIdx.x;
  const int c8 = id & 7;
  const int nb = (id >> 3) & 7;
  const int g = (id >> 6) * 8 + c8;  // group = (m, kslice)
  const int mb = g % mBlocks;
  const int ks = g / mBlocks;

  const int tid = threadIdx.x;
  const int lane = tid & 63;
  const int wave = tid >> 6;
  const int quad = lane >> 4;
  const int m16 = lane & 15;
  const int wm = (wave >> 1) * 64;
  const int wn = (wave & 1) * 64;

  const size_t rowBase = (size_t)mb * 128;
  const size_t colBase = (size_t)nb * 128;
  const int kBeg = ks * Kslice;

  const int srow = lane >> 2;
  const int g16 = lane & 3;
  const uint8_t* Asrc[2];
  const uint8_t* Bsrc[2];
  int dOff[2];
#pragma unroll
  for (int c = 0; c < 2; ++c) {
    int tr = wave * 32 + c * 16 + srow;
    int gs = g16 ^ ((tr >> 1) & 3);
    Asrc[c] = P + (rowBase + tr) * (size_t)MEMN + kBeg + gs * 16;
    Bsrc[c] = VT + (colBase + tr) * (size_t)MEMN + kBeg + gs * 16;
    dOff[c] = tr * 64 + g16 * 16;
  }

  auto stage = [&](int buf, int k0) {
#pragma unroll
    for (int c = 0; c < 2; ++c) {
      global_to_lds16(Asrc[c] + k0, &sA[buf][dOff[c]]);
      global_to_lds16(Bsrc[c] + k0, &sB[buf][dOff[c]]);
    }
  };

  float4v acc[4][4] = {};
  float4v accrs[4] = {};
  // rowsum only once per row-stripe: nb==0 AND even wave (waves 0/1 share wm!)
  const bool doRS = (nb == 0) && ((wave & 1) == 0);
  const long vone = 0x3838383838383838L;  // 8x fp8 e4m3 1.0

  const int nsteps = Kslice / 64;
  stage(0, 0);
  __syncthreads();  // drains vmcnt -> buf0 ready

  int cur = 0;
  for (int step = 0; step < nsteps; ++step) {
    if (step + 1 < nsteps) stage(cur ^ 1, (step + 1) * 64);  // issue, in flight

#pragma unroll
    for (int kk = 0; kk < 2; ++kk) {
      const int g8 = (kk * 4 + quad) ^ (m16 & 6);
      long af[4], bf[4];
#pragma unroll
      for (int i = 0; i < 4; ++i)
        af[i] = *(const long*)&sA[cur][(wm + i * 16 + m16) * 64 + g8 * 8];
#pragma unroll
      for (int j = 0; j < 4; ++j)
        bf[j] = *(const long*)&sB[cur][(wn + j * 16 + m16) * 64 + g8 * 8];
#pragma unroll
      for (int i = 0; i < 4; ++i) {
#pragma unroll
        for (int j = 0; j < 4; ++j)
          acc[i][j] = __builtin_amdgcn_mfma_f32_16x16x32_fp8_fp8(
              af[i], bf[j], acc[i][j], 0, 0, 0);
        if (doRS)
          accrs[i] = __builtin_amdgcn_mfma_f32_16x16x32_fp8_fp8(
              af[i], vone, accrs[i], 0, 0, 0);
      }
    }

    __syncthreads();  // drains prefetch (overlapped with MFMAs above)
    cur ^= 1;
  }

#pragma unroll
  for (int i = 0; i < 4; ++i) {
#pragma unroll
    for (int j = 0; j < 4; ++j) {
      size_t c = colBase + wn + j * 16 + m16;
#pragma unroll
      for (int rr = 0; rr < 4; ++rr) {
        size_t row = rowBase + wm + i * 16 + quad * 4 + rr;
        atomicAdd(&O32[row * 1024 + c], acc[i][j][rr]);
      }
    }
    if (doRS && m16 == 0) {
#pragma unroll
      for (int rr = 0; rr < 4; ++rr) {
        size_t row = rowBase + wm + i * 16 + quad * 4 + rr;
        atomicAdd(&rs32[row], accrs[i][rr]);
      }
    }
  }
}

// ---------------- launch ----------------

static inline void* wsalloc(char*& p, size_t bytes) {
  void* r = (void*)p;
  p += (bytes + 255) & ~(size_t)255;
  return r;
}

extern "C" void kernel_launch(void* const* d_in, const int* in_sizes, int n_in,
                              void* d_out, int out_size, void* d_ws,
                              size_t ws_size, hipStream_t stream) {
  const float* query = (const float*)d_in[0];
  const float* W_in = (const float*)d_in[1];
  const float* b_in = (const float*)d_in[2];
  const float* W_e1 = (const float*)d_in[3];
  const float* b_e1 = (const float*)d_in[4];
  const float* W_e2 = (const float*)d_in[5];
  const float* b_e2 = (const float*)d_in[6];
  const float* W_k = (const float*)d_in[7];
  const float* b_k = (const float*)d_in[8];
  const float* memk = (const float*)d_in[9];
  const float* memv = (const float*)d_in[10];
  const float* W_r1 = (const float*)d_in[11];
  const float* b_r1 = (const float*)d_in[12];
  const float* W_r2 = (const float*)d_in[13];
  const float* b_r2 = (const float*)d_in[14];
  float* out = (float*)d_out;

  char* p = (char*)d_ws;
  _Float16* q16 = (_Float16*)wsalloc(p, (size_t)NQ * EMB * 2);
  _Float16* WinT = (_Float16*)wsalloc(p, (size_t)HID * EMB * 2);
  _Float16* We1T = (_Float16*)wsalloc(p, (size_t)2 * HID * HID * 2);
  _Float16* We2T = (_Float16*)wsalloc(p, (size_t)HID * 2 * HID * 2);
  _Float16* WkT = (_Float16*)wsalloc(p, (size_t)HID * HID * 2);
  _Float16* Wr1T = (_Float16*)wsalloc(p, (size_t)2 * HID * 2 * HID * 2);
  _Float16* Wr2T = (_Float16*)wsalloc(p, (size_t)EMB * 2 * HID * 2);
  uint8_t* memk8 = (uint8_t*)wsalloc(p, (size_t)MEMN * HID);
  uint8_t* memvT8 = (uint8_t*)wsalloc(p, (size_t)HID * MEMN);
  _Float16* x16 = (_Float16*)wsalloc(p, (size_t)NQ * HID * 2);
  _Float16* h16 = (_Float16*)wsalloc(p, (size_t)NQ * 2 * HID * 2);
  uint8_t* key8 = (uint8_t*)wsalloc(p, (size_t)NQ * HID);
  _Float16* comb16 = (_Float16*)wsalloc(p, (size_t)NQ * 2 * HID * 2);
  _Float16* r16 = (_Float16*)wsalloc(p, (size_t)NQ * 2 * HID * 2);
  float* O32 = (float*)wsalloc(p, (size_t)NQ * HID * 4);
  float* rs32 = (float*)wsalloc(p, (size_t)NQ * 4);

  // P buffer (fp8): chunk M if ws is too small (constant per ws_size).
  size_t fixedBytes = (size_t)(p - (char*)d_ws);
  size_t Mc = NQ;
  while (Mc > 128 && fixedBytes + Mc * (size_t)MEMN > ws_size) Mc >>= 1;
  uint8_t* P8 = (uint8_t*)wsalloc(p, Mc * (size_t)MEMN);

  auto cvt = [&](const float* in, _Float16* o, size_t n) {
    cvt_f32_to_f16<<<dim3((unsigned)((n / 4 + 255) / 256)), 256, 0, stream>>>(in, o, n);
  };
  auto tr = [&](const float* in, _Float16* o, int R, int C) {
    transpose_cvt<<<dim3(C / 32, R / 32), dim3(32, 8), 0, stream>>>(in, o, R, C);
  };

  cvt(query, q16, (size_t)NQ * EMB);
  cvt_f32_to_f8<<<dim3((unsigned)((size_t)MEMN * HID / 4 / 256)), 256, 0, stream>>>(
      memk, memk8, (size_t)MEMN * HID);
  tr(W_in, WinT, EMB, HID);
  tr(W_e1, We1T, HID, 2 * HID);
  tr(W_e2, We2T, 2 * HID, HID);
  tr(W_k, WkT, HID, HID);
  tr(W_r1, Wr1T, 2 * HID, 2 * HID);
  tr(W_r2, Wr2T, 2 * HID, EMB);
  transpose_cvt_f8<<<dim3(HID / 32, MEMN / 32), dim3(32, 8), 0, stream>>>(
      memv, memvT8, MEMN, HID);

  // x = query @ W_in + b_in
  gemm_bt<EPI_H16><<<dim3(HID / 128, NQ / 128), 256, 0, stream>>>(
      q16, EMB, WinT, EMB, b_in, x16, HID, EMB, 0.f);
  // h = gelu(x @ W_e1 + b_e1)
  gemm_bt<EPI_GELU_H16><<<dim3(2 * HID / 128, NQ / 128), 256, 0, stream>>>(
      x16, HID, We1T, HID, b_e1, h16, 2 * HID, HID, 0.f);
  // encoded = h @ W_e2 + b_e2  -> left half of combined (ldc = 2*HID)
  gemm_bt<EPI_H16><<<dim3(HID / 128, NQ / 128), 256, 0, stream>>>(
      h16, 2 * HID, We2T, 2 * HID, b_e2, comb16, 2 * HID, 2 * HID, 0.f);
  // key8 = fp8(encoded @ W_k + b_k)   (A = combined left half via lda = 2*HID)
  gemm_bt<EPI_H8><<<dim3(HID / 128, NQ / 128), 256, 0, stream>>>(
      comb16, 2 * HID, WkT, HID, b_k, key8, HID, HID, 0.f);

  // zero attention accumulators (harness poisons ws every call)
  hipMemsetAsync(O32, 0, (size_t)NQ * HID * 4, stream);
  hipMemsetAsync(rs32, 0, (size_t)NQ * 4, stream);

  const float scale = 0.03125f;  // 1/sqrt(HID)
  const int Kslice = MEMN / KSPLIT;
  for (size_t m0 = 0; m0 < NQ; m0 += Mc) {
    int ny = (int)(Mc / 128);
    // P = fp8(exp(scale * key @ memk^T))   [Mc, MEMN]
    gemm_qk_fp8<<<dim3((unsigned)(MEMN / 128 * ny)), 256, 0, stream>>>(
        key8 + m0 * HID, memk8, P8, ny, scale);
    // O32[m0..] += P @ memv (split-K, fp32 atomics); rs32 += rowsum(P)
    gemm_pv_splitk_fp8<<<dim3((unsigned)(ny * KSPLIT * 8)), 256, 0, stream>>>(
        P8, memvT8, O32 + m0 * HID, rs32 + m0, Kslice, ny);
  }

  // retrieved = O32 / rs32 -> right half of combined
  normalize_out<<<dim3(NQ * HID / 4 / 256), 256, 0, stream>>>(O32, rs32, comb16);

  // r = gelu(combined @ W_r1 + b_r1)
  gemm_bt<EPI_GELU_H16><<<dim3(2 * HID / 128, NQ / 128), 256, 0, stream>>>(
      comb16, 2 * HID, Wr1T, 2 * HID, b_r1, r16, 2 * HID, 2 * HID, 0.f);
  // result = r @ W_r2 + b_r2  (fp32 out)
  gemm_bt<EPI_F32><<<dim3(EMB / 128, NQ / 128), 256, 0, stream>>>(
      r16, 2 * HID, Wr2T, 2 * HID, b_r2, out, EMB, 2 * HID, 0.f);

  (void)in_sizes; (void)n_in; (void)out_size;
}